// Round 2
// baseline (269.355 us; speedup 1.0000x reference)
//
#include <hip/hip_runtime.h>
#include <hip/hip_bf16.h>

// RandomShift: out[row, t] = x[row, t - s] if 0 <= t-s < T else 0
// x: [256, 160000] f32, s = shifts[row] - 16000 (row-uniform).
//
// R1 lesson: 4 scalar loads/lane (16B lane-stride) was VMEM-request-bound
// (267us, ~1.2 TB/s). Now both sides are aligned float4 (16B/lane coalesced):
// funnel-shift across the row-uniform sub-vec misalignment d = (-s) & 3 using
// __shfl_down for the neighbor vector; lane 63 of each wave reloads its
// neighbor (1-lane predicated load, ~1/64 extra traffic).

constexpr int T_LEN       = 160000;
constexpr int MAX_SHIFT   = 16000;       // int(T * 0.1)
constexpr int ROWS        = 32 * 8;      // B * M
constexpr int VEC_PER_ROW = T_LEN / 4;   // 40000 float4s per row

__global__ __launch_bounds__(256) void RandomShift_33079838113837_kernel(
    const float* __restrict__ x,
    const int*   __restrict__ shifts,
    float*       __restrict__ out) {
    const int row = blockIdx.y;                 // wave-uniform
    const int s   = shifts[row] - MAX_SHIFT;    // row-uniform shift

    const float4* __restrict__ xr4 =
        reinterpret_cast<const float4*>(x + (size_t)row * T_LEN);

    const int v    = blockIdx.x * blockDim.x + threadIdx.x;  // float4 idx in row
    const int t0   = v * 4;
    const int src0 = t0 - s;

    const int d = (-s) & 3;            // row-uniform sub-vector misalignment
    const int k = (src0 - d) >> 2;     // floor((t0 - s)/4), exact (src0-d is mult of 4)

    // Clamp for memory safety; OOB elements are zeroed at the end.
    const int kc = min(max(k, 0), VEC_PER_ROW - 1);
    float4 A = xr4[kc];                // fully coalesced 16B/lane
    float4 B = A;

    if (d != 0) {                      // wave-uniform branch (d row-uniform)
        B.x = __shfl_down(A.x, 1);
        B.y = __shfl_down(A.y, 1);
        B.z = __shfl_down(A.z, 1);
        B.w = __shfl_down(A.w, 1);
        if ((threadIdx.x & 63) == 63) {            // wave-edge lane reloads
            const int kc2 = min(max(k + 1, 0), VEC_PER_ROW - 1);
            B = xr4[kc2];
        }
    }

    float4 r;
    switch (d) {                       // wave-uniform
        case 0: r = A; break;
        case 1: r = make_float4(A.y, A.z, A.w, B.x); break;
        case 2: r = make_float4(A.z, A.w, B.x, B.y); break;
        default: r = make_float4(A.w, B.x, B.y, B.z); break;
    }

    // Zero out-of-range source elements (left/right fill regions).
    r.x = (src0 >= 0     && src0 < T_LEN)     ? r.x : 0.0f;
    r.y = (src0 + 1 >= 0 && src0 + 1 < T_LEN) ? r.y : 0.0f;
    r.z = (src0 + 2 >= 0 && src0 + 2 < T_LEN) ? r.z : 0.0f;
    r.w = (src0 + 3 >= 0 && src0 + 3 < T_LEN) ? r.w : 0.0f;

    if (v < VEC_PER_ROW) {
        float* outr = out + (size_t)row * T_LEN;
        *reinterpret_cast<float4*>(outr + t0) = r;
    }
}

extern "C" void kernel_launch(void* const* d_in, const int* in_sizes, int n_in,
                              void* d_out, int out_size, void* d_ws, size_t ws_size,
                              hipStream_t stream) {
    const float* x      = (const float*)d_in[0];
    const int*   shifts = (const int*)d_in[1];
    float*       out    = (float*)d_out;

    const int block = 256;
    dim3 grid((VEC_PER_ROW + block - 1) / block, ROWS, 1);  // 157 x 256

    RandomShift_33079838113837_kernel<<<grid, block, 0, stream>>>(x, shifts, out);
}